// Round 5
// baseline (1475.967 us; speedup 1.0000x reference)
//
#include <hip/hip_runtime.h>

// Sparsemax attention: B=8, L=1024, S=1024, H=16, E=64, D=64, fp32 in/out.
// r5: pre-packed fp16 swizzled K/Q tiles in workspace; QK^T via fp16 MFMA;
// lazy running-max candidate filter; Newton sparsemax; float4 sparse A*V.

typedef _Float16 f16x8 __attribute__((ext_vector_type(8)));
typedef float    f32x4 __attribute__((ext_vector_type(4)));

constexpr int kB = 8, kL = 1024, kS = 1024, kH = 16, kE = 64, kD = 64;
constexpr int LT   = 16;        // L rows per block
constexpr int JT   = 128;       // S cols per staged K tile
constexpr int CAP  = 128;       // candidate capacity per row (mean ~27)
constexpr int KMAX = CAP / 16;  // Newton regs per lane

__device__ __forceinline__ float pk2(float a, float b) {
  auto h = __builtin_amdgcn_cvt_pkrtz(a, b);
  return __builtin_bit_cast(float, h);
}

// K -> fp16, per-(b,h,jt) 16KB tiles, unit u = jj*8 + (e8 ^ (jj&7))
__global__ __launch_bounds__(256) void prepack_k(const float* __restrict__ K,
                                                 float4* __restrict__ Kp) {
  const int gid = blockIdx.x * 256 + threadIdx.x;        // 1,048,576
  const int u = gid & 1023, jt = (gid >> 10) & 7, h = (gid >> 13) & 15, b = gid >> 17;
  const int jj = u >> 3, slot = u & 7, e8 = slot ^ (jj & 7);
  const int s = jt * 128 + jj;
  const float4* src = (const float4*)(K + (((size_t)(b * kS + s)) * kH + h) * kE + e8 * 8);
  const float4 c0 = src[0], c1 = src[1];
  Kp[gid] = make_float4(pk2(c0.x, c0.y), pk2(c0.z, c0.w), pk2(c1.x, c1.y), pk2(c1.z, c1.w));
}

// Q -> fp16 (scale folded), per-(b,h,lblk) 2KB tiles, same swizzle
__global__ __launch_bounds__(256) void prepack_q(const float* __restrict__ Q,
                                                 float4* __restrict__ Qp) {
  const int gid = blockIdx.x * 256 + threadIdx.x;        // 1,048,576
  const int u = gid & 127, lb = (gid >> 7) & 63, h = (gid >> 13) & 15, b = gid >> 17;
  const int jj = u >> 3, slot = u & 7, e8 = slot ^ (jj & 7);
  const int l = lb * 16 + jj;
  const float4* src = (const float4*)(Q + (((size_t)(b * kL + l)) * kH + h) * kE + e8 * 8);
  float4 c0 = src[0], c1 = src[1];
  c0.x *= .125f; c0.y *= .125f; c0.z *= .125f; c0.w *= .125f;
  c1.x *= .125f; c1.y *= .125f; c1.z *= .125f; c1.w *= .125f;
  Qp[gid] = make_float4(pk2(c0.x, c0.y), pk2(c0.z, c0.w), pk2(c1.x, c1.y), pk2(c1.z, c1.w));
}

__global__ __launch_bounds__(256, 4)
void sparsemax_attn(const float* __restrict__ Q, const float* __restrict__ K,
                    const float* __restrict__ V, float* __restrict__ O,
                    const float4* __restrict__ Kp, const float4* __restrict__ Qp,
                    int pre) {
  __shared__ float4 Ksh[JT * 8];       // 16 KB fp16 K tile (swizzled units)
  __shared__ float4 Qsh[LT * 8];       //  2 KB fp16 Q tile
  __shared__ float2 lists[LT * CAP];   // 16 KB (z, j-as-float)
  __shared__ int    cnt_s[LT];
  __shared__ float  rmax_s[LT][4];
  __shared__ float  tau_s[LT];

  const int t = threadIdx.x, lane = t & 63, rg = t >> 6;
  const int li = lane & 15, g = lane >> 4;
  const int bh = blockIdx.y, b = bh >> 4, h = bh & 15;
  const int l0 = blockIdx.x * LT;

  const float* Kbh = K + ((size_t)b * kS * kH + h) * kE;
  const float* Vb  = V + ((size_t)b * kS * kH + h) * kD;

  if (t < LT) cnt_s[t] = 0;
  if (pre) {
    if (t < 128) Qsh[t] = Qp[((size_t)((b * kH + h) * 64 + blockIdx.x)) * 128 + t];
  } else if (t < 128) {
    const int jj = t >> 3, e8 = t & 7;
    const float4* qp =
        (const float4*)(Q + (((size_t)(b * kL + l0 + jj)) * kH + h) * kE + e8 * 8);
    float4 q0 = qp[0], q1 = qp[1];
    q0.x *= .125f; q0.y *= .125f; q0.z *= .125f; q0.w *= .125f;
    q1.x *= .125f; q1.y *= .125f; q1.z *= .125f; q1.w *= .125f;
    Qsh[jj * 8 + (e8 ^ (jj & 7))] =
        make_float4(pk2(q0.x, q0.y), pk2(q0.z, q0.w), pk2(q1.x, q1.y), pk2(q1.z, q1.w));
  }

  float mloc[4] = {-3e38f, -3e38f, -3e38f, -3e38f};
  float run[4]  = {-3e38f, -3e38f, -3e38f, -3e38f};
  f16x8 a0, a1;

  for (int jt = 0; jt < kS / JT; ++jt) {
    __syncthreads();
    if (pre) {
      const float4* Kt = Kp + ((size_t)((b * kH + h) * 8 + jt)) * 1024;
#pragma unroll
      for (int i = 0; i < 4; ++i) Ksh[t + 256 * i] = Kt[t + 256 * i];
    } else {
#pragma unroll
      for (int i = 0; i < 4; ++i) {
        const int idx = t + 256 * i, jj = idx >> 3, e8 = idx & 7;
        const float4* kp =
            (const float4*)(Kbh + (size_t)(jt * JT + jj) * (kH * kE) + e8 * 8);
        const float4 c0 = kp[0], c1 = kp[1];
        Ksh[jj * 8 + (e8 ^ (jj & 7))] =
            make_float4(pk2(c0.x, c0.y), pk2(c0.z, c0.w), pk2(c1.x, c1.y), pk2(c1.z, c1.w));
      }
    }
    __syncthreads();
    if (jt == 0) {
      a0 = __builtin_bit_cast(f16x8, Qsh[li * 8 + ((0 + g) ^ (li & 7))]);
      a1 = __builtin_bit_cast(f16x8, Qsh[li * 8 + ((4 + g) ^ (li & 7))]);
    }

    f32x4 acc[2];
    acc[0] = f32x4{0.f, 0.f, 0.f, 0.f};
    acc[1] = f32x4{0.f, 0.f, 0.f, 0.f};
#pragma unroll
    for (int ct = 0; ct < 2; ++ct) {
      const int jl = rg * 32 + ct * 16 + li;
      const f16x8 b0 = __builtin_bit_cast(f16x8, Ksh[jl * 8 + ((0 + g) ^ (jl & 7))]);
      const f16x8 b1 = __builtin_bit_cast(f16x8, Ksh[jl * 8 + ((4 + g) ^ (jl & 7))]);
      acc[ct] = __builtin_amdgcn_mfma_f32_16x16x32_f16(a0, b0, acc[ct], 0, 0, 0);
      acc[ct] = __builtin_amdgcn_mfma_f32_16x16x32_f16(a1, b1, acc[ct], 0, 0, 0);
    }

    // per-lane running max always; cross-lane reduce only on even tiles
#pragma unroll
    for (int r = 0; r < 4; ++r)
      mloc[r] = fmaxf(mloc[r], fmaxf(acc[0][r], acc[1][r]));
    if ((jt & 1) == 0) {
#pragma unroll
      for (int r = 0; r < 4; ++r) {
        float mr = mloc[r];
        mr = fmaxf(mr, __shfl_xor(mr, 1));
        mr = fmaxf(mr, __shfl_xor(mr, 2));
        mr = fmaxf(mr, __shfl_xor(mr, 4));
        mr = fmaxf(mr, __shfl_xor(mr, 8));
        run[r] = mr;  // exact running max (mloc is cumulative)
      }
    }
    const int colbase = jt * JT + rg * 32 + li;
#pragma unroll
    for (int r = 0; r < 4; ++r) {
      const int row = g * 4 + r;
      const float thr = run[r] - 1.0f;  // lower bound on tau* -> superset filter
#pragma unroll
      for (int ct = 0; ct < 2; ++ct) {
        const float z = acc[ct][r];
        if (z > thr) {
          const int pos = atomicAdd(&cnt_s[row], 1);
          if (pos < CAP)
            lists[row * CAP + pos] = make_float2(z, __int_as_float(colbase + ct * 16));
        }
      }
    }
  }
  // final exact per-wave row max
#pragma unroll
  for (int r = 0; r < 4; ++r) {
    float mr = mloc[r];
    mr = fmaxf(mr, __shfl_xor(mr, 1));
    mr = fmaxf(mr, __shfl_xor(mr, 2));
    mr = fmaxf(mr, __shfl_xor(mr, 4));
    mr = fmaxf(mr, __shfl_xor(mr, 8));
    if (li == 0) rmax_s[g * 4 + r][rg] = mr;
  }
  __syncthreads();

  // ---- Newton: wave rg owns rows rg*4..+3; row rg*4+g, 16 lanes each ----
  const int q0 = rg * 4;
  {
    const int row = q0 + g;
    const int n   = cnt_s[row];
    const int nc  = min(n, CAP);
    float zr[KMAX];
#pragma unroll
    for (int k = 0; k < KMAX; ++k) {
      const int i = li + 16 * k;
      zr[k] = (i < nc) ? lists[row * CAP + i].x : -1e30f;
    }
    const float M =
        fmaxf(fmaxf(rmax_s[row][0], rmax_s[row][1]), fmaxf(rmax_s[row][2], rmax_s[row][3]));
    float t0 = M - 1.0f;
    for (int it = 0; it < 12; ++it) {
      float s = 0.f, c = 0.f;
#pragma unroll
      for (int k = 0; k < KMAX; ++k) {
        const float d = zr[k] - t0;
        if (d > 0.f) { s += d; c += 1.f; }
      }
      s += __shfl_xor(s, 1); c += __shfl_xor(c, 1);
      s += __shfl_xor(s, 2); c += __shfl_xor(c, 2);
      s += __shfl_xor(s, 4); c += __shfl_xor(c, 4);
      s += __shfl_xor(s, 8); c += __shfl_xor(c, 8);
      const float delta = (s - 1.0f) / fmaxf(c, 1.f);
      t0 += fmaxf(delta, 0.f);
      if (__all(delta <= 1e-6f)) break;
    }
    if (li == 0) tau_s[row] = t0;
  }

  // ---- sparse A*V: 4 candidates concurrent (one per g), float4 over dims ----
#pragma unroll 1
  for (int r4 = 0; r4 < 4; ++r4) {
    const int row = q0 + r4;
    const int n   = cnt_s[row];
    const size_t obase = (((size_t)(b * kL + l0 + row)) * kH + h) * kD;
    if (n <= CAP) {
      const float tau = tau_s[row];
      f32x4 o4 = {0.f, 0.f, 0.f, 0.f};
      for (int i = g; i < n; i += 4) {
        const float2 e = lists[row * CAP + i];
        const float  p = fmaxf(e.x - tau, 0.f);
        const float4 v =
            ((const float4*)(Vb + (size_t)__float_as_int(e.y) * (kH * kD)))[li];
        o4.x = fmaf(p, v.x, o4.x);
        o4.y = fmaf(p, v.y, o4.y);
        o4.z = fmaf(p, v.z, o4.z);
        o4.w = fmaf(p, v.w, o4.w);
      }
#pragma unroll
      for (int off = 16; off < 64; off <<= 1) {
        o4.x += __shfl_xor(o4.x, off);
        o4.y += __shfl_xor(o4.y, off);
        o4.z += __shfl_xor(o4.z, off);
        o4.w += __shfl_xor(o4.w, off);
      }
      if (g == 0)
        ((float4*)(O + obase))[li] = make_float4(o4.x, o4.y, o4.z, o4.w);
    } else {
      // ---- cold exact fallback (list overflow): dense recompute ----
      float scr2[16];
      for (int cc = 0; cc < 16; ++cc) {
        const int j = lane + 64 * cc;
        const float* kr = Kbh + (size_t)j * (kH * kE);
        float zz = 0.f;
        for (int e8 = 0; e8 < 8; ++e8) {
          const f16x8 qh = __builtin_bit_cast(f16x8, Qsh[row * 8 + (e8 ^ (row & 7))]);
          const float4* kp = (const float4*)(kr + e8 * 8);
          const float4 c0 = kp[0], c1 = kp[1];
          zz += (float)qh[0] * c0.x + (float)qh[1] * c0.y + (float)qh[2] * c0.z +
                (float)qh[3] * c0.w + (float)qh[4] * c1.x + (float)qh[5] * c1.y +
                (float)qh[6] * c1.z + (float)qh[7] * c1.w;
        }
        scr2[cc] = zz;
      }
      const float M2 =
          fmaxf(fmaxf(rmax_s[row][0], rmax_s[row][1]), fmaxf(rmax_s[row][2], rmax_s[row][3]));
      float t0 = M2 - 1.0f;
      for (int it = 0; it < 48; ++it) {
        float s = 0.f, c = 0.f;
        for (int cc = 0; cc < 16; ++cc) {
          const float d = scr2[cc] - t0;
          if (d > 0.f) { s += d; c += 1.f; }
        }
        for (int off = 32; off; off >>= 1) { s += __shfl_xor(s, off); c += __shfl_xor(c, off); }
        const float delta = (s - 1.0f) / fmaxf(c, 1.f);
        if (delta <= 1e-7f) break;
        t0 += delta;
      }
      float oacc = 0.f;
      for (int cc = 0; cc < 16; ++cc)
        for (int src = 0; src < 64; ++src) {
          const float z = __shfl(scr2[cc], src);
          const float p = z - t0;
          if (p > 0.f)
            oacc = fmaf(p, Vb[(size_t)(src + 64 * cc) * (kH * kD) + lane], oacc);
        }
      O[obase + lane] = oacc;
    }
  }
}

extern "C" void kernel_launch(void* const* d_in, const int* in_sizes, int n_in,
                              void* d_out, int out_size, void* d_ws, size_t ws_size,
                              hipStream_t stream) {
  (void)in_sizes; (void)n_in; (void)out_size;
  const float* Q = (const float*)d_in[0];
  const float* K = (const float*)d_in[1];
  const float* V = (const float*)d_in[2];
  float* O = (float*)d_out;

  const int pre = (ws_size >= (size_t)32 * 1024 * 1024) ? 1 : 0;
  float4* Kp = (float4*)d_ws;
  float4* Qp = Kp + 1048576;  // +16 MB

  if (pre) {
    prepack_k<<<4096, 256, 0, stream>>>(K, Kp);
    prepack_q<<<4096, 256, 0, stream>>>(Q, Qp);
  }
  dim3 grid(kL / LT, kB * kH);
  sparsemax_attn<<<grid, dim3(256), 0, stream>>>(Q, K, V, O, Kp, Qp, pre);
}

// Round 6
// 1391.635 us; speedup vs baseline: 1.0606x; 1.0606x over previous
//
#include <hip/hip_runtime.h>

// Sparsemax attention: B=8, L=1024, S=1024, H=16, E=64, D=64, fp32 in/out.
// r6: fused fp16 MFMA QK^T (revert r5 workspace prepack), XCD-aware 1-D grid,
// 4 blocks/CU, lazy running-max candidate filter, Newton sparsemax,
// 4-wide float4 sparse A*V.

typedef _Float16 f16x8 __attribute__((ext_vector_type(8)));
typedef float    f32x4 __attribute__((ext_vector_type(4)));

constexpr int kB = 8, kL = 1024, kS = 1024, kH = 16, kE = 64, kD = 64;
constexpr int LT   = 16;        // L rows per block
constexpr int JT   = 128;       // S cols per staged K tile
constexpr int CAP  = 128;       // candidate capacity per row (observed ~5-30)
constexpr int KMAX = CAP / 16;  // Newton regs per lane

__device__ __forceinline__ float pk2(float a, float b) {
  auto h = __builtin_amdgcn_cvt_pkrtz(a, b);
  return __builtin_bit_cast(float, h);
}

__global__ __launch_bounds__(256, 4)
void sparsemax_attn(const float* __restrict__ Q, const float* __restrict__ K,
                    const float* __restrict__ V, float* __restrict__ O) {
  __shared__ float4 Ksh[JT * 8];       // 16 KB fp16 K tile, swizzled slot^(row&7)
  __shared__ float4 Qsh[LT * 8];       //  2 KB fp16 Q tile (scale folded)
  __shared__ float2 lists[LT * CAP];   // 16 KB (z, j-as-float)
  __shared__ int    cnt_s[LT];
  __shared__ float  rmax_s[LT][4];
  __shared__ float  tau_s[LT];

  const int t = threadIdx.x, lane = t & 63, rg = t >> 6;
  const int li = lane & 15, g = lane >> 4;

  // XCD-aware remap: round-robin id%8 -> XCD; same-XCD blocks share bh.
  const int id  = blockIdx.x;
  const int xcd = id & 7, kk = id >> 3;
  const int bh  = xcd * 16 + (kk >> 6);     // 16 bh per XCD, slow-varying
  const int b   = bh >> 4, h = bh & 15;
  const int l0  = (kk & 63) * LT;

  const float* Kbh = K + ((size_t)b * kS * kH + h) * kE;
  const float* Vb  = V + ((size_t)b * kS * kH + h) * kD;

  if (t < LT) cnt_s[t] = 0;
  if (t < 128) {  // stage Q: 16 rows x 8 slots of 8 halfs
    const int jj = t >> 3, e8 = t & 7;
    const float4* qp =
        (const float4*)(Q + (((size_t)(b * kL + l0 + jj)) * kH + h) * kE + e8 * 8);
    float4 q0 = qp[0], q1 = qp[1];
    q0.x *= .125f; q0.y *= .125f; q0.z *= .125f; q0.w *= .125f;
    q1.x *= .125f; q1.y *= .125f; q1.z *= .125f; q1.w *= .125f;
    Qsh[jj * 8 + (e8 ^ (jj & 7))] =
        make_float4(pk2(q0.x, q0.y), pk2(q0.z, q0.w), pk2(q1.x, q1.y), pk2(q1.z, q1.w));
  }

  float mloc[4] = {-3e38f, -3e38f, -3e38f, -3e38f};
  float run[4]  = {-3e38f, -3e38f, -3e38f, -3e38f};
  f16x8 a0, a1;

  for (int jt = 0; jt < kS / JT; ++jt) {
    __syncthreads();
    // stage K tile: 128 rows x 64 halfs; coalesced fp32 loads + pkrtz cvt
#pragma unroll
    for (int i = 0; i < 4; ++i) {
      const int idx = t + 256 * i, jj = idx >> 3, e8 = idx & 7;
      const float4* kp =
          (const float4*)(Kbh + (size_t)(jt * JT + jj) * (kH * kE) + e8 * 8);
      const float4 c0 = kp[0], c1 = kp[1];
      Ksh[jj * 8 + (e8 ^ (jj & 7))] =
          make_float4(pk2(c0.x, c0.y), pk2(c0.z, c0.w), pk2(c1.x, c1.y), pk2(c1.z, c1.w));
    }
    __syncthreads();
    if (jt == 0) {  // a-frags: Q[row=li][k = ks*32 + g*8 ..+8]
      a0 = __builtin_bit_cast(f16x8, Qsh[li * 8 + ((0 + g) ^ (li & 7))]);
      a1 = __builtin_bit_cast(f16x8, Qsh[li * 8 + ((4 + g) ^ (li & 7))]);
    }

    f32x4 acc[2];
    acc[0] = f32x4{0.f, 0.f, 0.f, 0.f};
    acc[1] = f32x4{0.f, 0.f, 0.f, 0.f};
#pragma unroll
    for (int ct = 0; ct < 2; ++ct) {  // wave rg covers cols rg*32 + ct*16 + li
      const int jl = rg * 32 + ct * 16 + li;
      const f16x8 b0 = __builtin_bit_cast(f16x8, Ksh[jl * 8 + ((0 + g) ^ (jl & 7))]);
      const f16x8 b1 = __builtin_bit_cast(f16x8, Ksh[jl * 8 + ((4 + g) ^ (jl & 7))]);
      acc[ct] = __builtin_amdgcn_mfma_f32_16x16x32_f16(a0, b0, acc[ct], 0, 0, 0);
      acc[ct] = __builtin_amdgcn_mfma_f32_16x16x32_f16(a1, b1, acc[ct], 0, 0, 0);
    }

    // per-lane running max always; cross-lane reduce only on even tiles
#pragma unroll
    for (int r = 0; r < 4; ++r)
      mloc[r] = fmaxf(mloc[r], fmaxf(acc[0][r], acc[1][r]));
    if ((jt & 1) == 0) {
#pragma unroll
      for (int r = 0; r < 4; ++r) {
        float mr = mloc[r];
        mr = fmaxf(mr, __shfl_xor(mr, 1));
        mr = fmaxf(mr, __shfl_xor(mr, 2));
        mr = fmaxf(mr, __shfl_xor(mr, 4));
        mr = fmaxf(mr, __shfl_xor(mr, 8));
        run[r] = mr;  // exact running max (mloc is cumulative)
      }
    }
    const int colbase = jt * JT + rg * 32 + li;
#pragma unroll
    for (int r = 0; r < 4; ++r) {
      const int row = g * 4 + r;
      const float thr = run[r] - 1.0f;  // lower bound on tau* -> superset filter
#pragma unroll
      for (int ct = 0; ct < 2; ++ct) {
        const float z = acc[ct][r];
        if (z > thr) {
          const int pos = atomicAdd(&cnt_s[row], 1);
          if (pos < CAP)
            lists[row * CAP + pos] = make_float2(z, __int_as_float(colbase + ct * 16));
        }
      }
    }
  }
  // final exact per-wave row max
#pragma unroll
  for (int r = 0; r < 4; ++r) {
    float mr = mloc[r];
    mr = fmaxf(mr, __shfl_xor(mr, 1));
    mr = fmaxf(mr, __shfl_xor(mr, 2));
    mr = fmaxf(mr, __shfl_xor(mr, 4));
    mr = fmaxf(mr, __shfl_xor(mr, 8));
    if (li == 0) rmax_s[g * 4 + r][rg] = mr;
  }
  __syncthreads();

  // ---- Newton: wave rg owns rows rg*4..+3; row rg*4+g, 16 lanes each ----
  const int q0 = rg * 4;
  {
    const int row = q0 + g;
    const int n   = cnt_s[row];
    const int nc  = min(n, CAP);
    float zr[KMAX];
#pragma unroll
    for (int k = 0; k < KMAX; ++k) {
      const int i = li + 16 * k;
      zr[k] = (i < nc) ? lists[row * CAP + i].x : -1e30f;
    }
    const float M =
        fmaxf(fmaxf(rmax_s[row][0], rmax_s[row][1]), fmaxf(rmax_s[row][2], rmax_s[row][3]));
    float t0 = M - 1.0f;
    for (int it = 0; it < 12; ++it) {
      float s = 0.f, c = 0.f;
#pragma unroll
      for (int k = 0; k < KMAX; ++k) {
        const float d = zr[k] - t0;
        if (d > 0.f) { s += d; c += 1.f; }
      }
      s += __shfl_xor(s, 1); c += __shfl_xor(c, 1);
      s += __shfl_xor(s, 2); c += __shfl_xor(c, 2);
      s += __shfl_xor(s, 4); c += __shfl_xor(c, 4);
      s += __shfl_xor(s, 8); c += __shfl_xor(c, 8);
      const float delta = (s - 1.0f) / fmaxf(c, 1.f);
      t0 += fmaxf(delta, 0.f);
      if (__all(delta <= 1e-6f)) break;
    }
    if (li == 0) tau_s[row] = t0;
  }

  // ---- sparse A*V: 4 candidates concurrent (one per g), float4 over dims ----
#pragma unroll 1
  for (int r4 = 0; r4 < 4; ++r4) {
    const int row = q0 + r4;
    const int n   = cnt_s[row];
    const size_t obase = (((size_t)(b * kL + l0 + row)) * kH + h) * kD;
    if (n <= CAP) {
      const float tau = tau_s[row];
      f32x4 o4 = {0.f, 0.f, 0.f, 0.f};
      for (int i = g; i < n; i += 4) {
        const float2 e = lists[row * CAP + i];
        const float  p = fmaxf(e.x - tau, 0.f);
        const float4 v =
            ((const float4*)(Vb + (size_t)__float_as_int(e.y) * (kH * kD)))[li];
        o4.x = fmaf(p, v.x, o4.x);
        o4.y = fmaf(p, v.y, o4.y);
        o4.z = fmaf(p, v.z, o4.z);
        o4.w = fmaf(p, v.w, o4.w);
      }
#pragma unroll
      for (int off = 16; off < 64; off <<= 1) {
        o4.x += __shfl_xor(o4.x, off);
        o4.y += __shfl_xor(o4.y, off);
        o4.z += __shfl_xor(o4.z, off);
        o4.w += __shfl_xor(o4.w, off);
      }
      if (g == 0)
        ((float4*)(O + obase))[li] = make_float4(o4.x, o4.y, o4.z, o4.w);
    } else {
      // ---- cold exact fallback (list overflow): dense recompute ----
      float scr2[16];
      for (int cc = 0; cc < 16; ++cc) {
        const int j = lane + 64 * cc;
        const float* kr = Kbh + (size_t)j * (kH * kE);
        float zz = 0.f;
        for (int e8 = 0; e8 < 8; ++e8) {
          const f16x8 qh = __builtin_bit_cast(f16x8, Qsh[row * 8 + (e8 ^ (row & 7))]);
          const float4* kp = (const float4*)(kr + e8 * 8);
          const float4 c0 = kp[0], c1 = kp[1];
          zz += (float)qh[0] * c0.x + (float)qh[1] * c0.y + (float)qh[2] * c0.z +
                (float)qh[3] * c0.w + (float)qh[4] * c1.x + (float)qh[5] * c1.y +
                (float)qh[6] * c1.z + (float)qh[7] * c1.w;
        }
        scr2[cc] = zz;
      }
      const float M2 =
          fmaxf(fmaxf(rmax_s[row][0], rmax_s[row][1]), fmaxf(rmax_s[row][2], rmax_s[row][3]));
      float t0 = M2 - 1.0f;
      for (int it = 0; it < 48; ++it) {
        float s = 0.f, c = 0.f;
        for (int cc = 0; cc < 16; ++cc) {
          const float d = scr2[cc] - t0;
          if (d > 0.f) { s += d; c += 1.f; }
        }
        for (int off = 32; off; off >>= 1) { s += __shfl_xor(s, off); c += __shfl_xor(c, off); }
        const float delta = (s - 1.0f) / fmaxf(c, 1.f);
        if (delta <= 1e-7f) break;
        t0 += delta;
      }
      float oacc = 0.f;
      for (int cc = 0; cc < 16; ++cc)
        for (int src = 0; src < 64; ++src) {
          const float z = __shfl(scr2[cc], src);
          const float p = z - t0;
          if (p > 0.f)
            oacc = fmaf(p, Vb[(size_t)(src + 64 * cc) * (kH * kD) + lane], oacc);
        }
      O[obase + lane] = oacc;
    }
  }
}

extern "C" void kernel_launch(void* const* d_in, const int* in_sizes, int n_in,
                              void* d_out, int out_size, void* d_ws, size_t ws_size,
                              hipStream_t stream) {
  (void)in_sizes; (void)n_in; (void)out_size; (void)d_ws; (void)ws_size;
  const float* Q = (const float*)d_in[0];
  const float* K = (const float*)d_in[1];
  const float* V = (const float*)d_in[2];
  float* O = (float*)d_out;
  sparsemax_attn<<<dim3(kB * kH * (kL / LT)), dim3(256), 0, stream>>>(Q, K, V, O);
}

// Round 7
// 564.980 us; speedup vs baseline: 2.6124x; 2.4632x over previous
//
#include <hip/hip_runtime.h>

// Sparsemax attention: B=8, L=1024, S=1024, H=16, E=64, D=64, fp32 in/out.
// r7 = r4 kernel verbatim (known-good 555 us) + XCD-aware 1-D grid remap ONLY.
// QK^T via fp16 MFMA (16x16x32), streaming candidate filter (z > rowmax-1),
// Newton sparsemax on tiny candidate lists, sparse A*V.

typedef _Float16 f16x8 __attribute__((ext_vector_type(8)));
typedef float    f32x4 __attribute__((ext_vector_type(4)));

constexpr int kB = 8, kL = 1024, kS = 1024, kH = 16, kE = 64, kD = 64;
constexpr int LT   = 16;          // L rows per block
constexpr int JT   = 128;         // S cols per staged K tile
constexpr int CAP  = 192;         // candidate capacity per row (expected ~30)
constexpr int KMAX = CAP / 16;    // Newton regs per lane (16 lanes per row)

__device__ __forceinline__ float pk2(float a, float b) {
  auto h = __builtin_amdgcn_cvt_pkrtz(a, b);   // __fp16 ext_vector_type(2)
  return __builtin_bit_cast(float, h);
}

__global__ __launch_bounds__(256, 3)
void sparsemax_attn(const float* __restrict__ Q, const float* __restrict__ K,
                    const float* __restrict__ V, float* __restrict__ O) {
  __shared__ float4 Ksh[JT * 8];       // 16 KB fp16 K tile, swizzled slot^(row&7)
  __shared__ float4 Qsh[LT * 8];       //  2 KB fp16 Q tile (scale folded)
  __shared__ float2 lists[LT * CAP];   // 24 KB (z, j-as-float)
  __shared__ int    cnt_s[LT];
  __shared__ float  rmax_s[LT][4];
  __shared__ float  tau_s[LT];

  const int t = threadIdx.x, lane = t & 63, rg = t >> 6;
  const int li = lane & 15, g = lane >> 4;

  // XCD-aware remap (ONLY change vs r4): round-robin id%8 -> XCD;
  // blocks resident on one XCD share few (b,h) -> K tile L2 locality.
  const int id  = blockIdx.x;
  const int xcd = id & 7, kk = id >> 3;
  const int bh  = xcd * 16 + (kk >> 6);   // 16 bh per XCD, slow-varying
  const int b   = bh >> 4, h = bh & 15;
  const int l0  = (kk & 63) * LT;

  const float* Kbh = K + ((size_t)b * kS * kH + h) * kE;
  const float* Vb  = V + ((size_t)b * kS * kH + h) * kD;

  if (t < LT) cnt_s[t] = 0;
  if (t < 128) {  // stage Q: 16 rows x 8 slots of 8 halfs
    const int jj = t >> 3, e8 = t & 7;
    const float4* qp =
        (const float4*)(Q + (((size_t)(b * kL + l0 + jj)) * kH + h) * kE + e8 * 8);
    float4 q0 = qp[0], q1 = qp[1];
    q0.x *= .125f; q0.y *= .125f; q0.z *= .125f; q0.w *= .125f;
    q1.x *= .125f; q1.y *= .125f; q1.z *= .125f; q1.w *= .125f;
    Qsh[jj * 8 + (e8 ^ (jj & 7))] =
        make_float4(pk2(q0.x, q0.y), pk2(q0.z, q0.w), pk2(q1.x, q1.y), pk2(q1.z, q1.w));
  }

  float run[4] = {-1e30f, -1e30f, -1e30f, -1e30f};
  f16x8 a0, a1;

  for (int jt = 0; jt < kS / JT; ++jt) {
    __syncthreads();
    // stage K tile: 128 rows x 64 halfs; coalesced fp32 loads + pkrtz cvt
#pragma unroll
    for (int i = 0; i < 4; ++i) {
      const int idx = t + 256 * i, jj = idx >> 3, e8 = idx & 7;
      const float4* kp =
          (const float4*)(Kbh + (size_t)(jt * JT + jj) * (kH * kE) + e8 * 8);
      const float4 c0 = kp[0], c1 = kp[1];
      Ksh[jj * 8 + (e8 ^ (jj & 7))] =
          make_float4(pk2(c0.x, c0.y), pk2(c0.z, c0.w), pk2(c1.x, c1.y), pk2(c1.z, c1.w));
    }
    __syncthreads();
    if (jt == 0) {  // a-frags: Q[row=li][k = ks*32 + g*8 ..+8]
      a0 = __builtin_bit_cast(f16x8, Qsh[li * 8 + ((0 + g) ^ (li & 7))]);
      a1 = __builtin_bit_cast(f16x8, Qsh[li * 8 + ((4 + g) ^ (li & 7))]);
    }

    f32x4 acc[2];
    acc[0] = f32x4{0.f, 0.f, 0.f, 0.f};
    acc[1] = f32x4{0.f, 0.f, 0.f, 0.f};
#pragma unroll
    for (int ct = 0; ct < 2; ++ct) {  // wave rg covers cols rg*32 + ct*16 + li
      const int jl = rg * 32 + ct * 16 + li;
      const f16x8 b0 = __builtin_bit_cast(f16x8, Ksh[jl * 8 + ((0 + g) ^ (jl & 7))]);
      const f16x8 b1 = __builtin_bit_cast(f16x8, Ksh[jl * 8 + ((4 + g) ^ (jl & 7))]);
      acc[ct] = __builtin_amdgcn_mfma_f32_16x16x32_f16(a0, b0, acc[ct], 0, 0, 0);
      acc[ct] = __builtin_amdgcn_mfma_f32_16x16x32_f16(a1, b1, acc[ct], 0, 0, 0);
    }

    // filter: C-layout row = g*4+r, col = lane&15 (+ct*16)
#pragma unroll
    for (int r = 0; r < 4; ++r) {
      const int row = g * 4 + r;
      float mr = fmaxf(acc[0][r], acc[1][r]);
      mr = fmaxf(mr, __shfl_xor(mr, 1));
      mr = fmaxf(mr, __shfl_xor(mr, 2));
      mr = fmaxf(mr, __shfl_xor(mr, 4));
      mr = fmaxf(mr, __shfl_xor(mr, 8));
      run[r] = fmaxf(run[r], mr);
      const float thr = run[r] - 1.0f;
#pragma unroll
      for (int ct = 0; ct < 2; ++ct) {
        const float z = acc[ct][r];
        if (z > thr) {
          const int pos = atomicAdd(&cnt_s[row], 1);
          if (pos < CAP)
            lists[row * CAP + pos] =
                make_float2(z, __int_as_float(jt * JT + rg * 32 + ct * 16 + li));
        }
      }
    }
  }
  if (li == 0) {
#pragma unroll
    for (int r = 0; r < 4; ++r) rmax_s[g * 4 + r][rg] = run[r];
  }
  __syncthreads();

  // ---- Newton: wave rg owns rows rg*4..+3; 16 lanes per row concurrently ----
  const int q0 = rg * 4;
  {
    const int row = q0 + g;
    const int n   = cnt_s[row];
    const int nc  = min(n, CAP);
    float zr[KMAX];
#pragma unroll
    for (int k = 0; k < KMAX; ++k) {
      const int i = li + 16 * k;
      zr[k] = (i < nc) ? lists[row * CAP + i].x : -1e30f;
    }
    const float M =
        fmaxf(fmaxf(rmax_s[row][0], rmax_s[row][1]), fmaxf(rmax_s[row][2], rmax_s[row][3]));
    float t0 = M - 1.0f;
    for (int it = 0; it < 14; ++it) {
      float s = 0.f, c = 0.f;
#pragma unroll
      for (int k = 0; k < KMAX; ++k) {
        const float d = zr[k] - t0;
        if (d > 0.f) { s += d; c += 1.f; }
      }
      s += __shfl_xor(s, 1); c += __shfl_xor(c, 1);
      s += __shfl_xor(s, 2); c += __shfl_xor(c, 2);
      s += __shfl_xor(s, 4); c += __shfl_xor(c, 4);
      s += __shfl_xor(s, 8); c += __shfl_xor(c, 8);
      const float delta = (s - 1.0f) / fmaxf(c, 1.f);
      t0 += fmaxf(delta, 0.f);
      if (__all(delta <= 1e-6f)) break;
    }
    if (li == 0) tau_s[row] = t0;
  }

  // ---- sparse A*V: lane = output dim d ----
#pragma unroll 1
  for (int r4 = 0; r4 < 4; ++r4) {
    const int row = q0 + r4;
    const int n   = cnt_s[row];
    float oacc = 0.f;
    if (n <= CAP) {
      const float tau = tau_s[row];
      const float4* lp = (const float4*)(lists + row * CAP);
      const int np = n >> 1;
      int i2 = 0;
      for (; i2 + 2 <= np; i2 += 2) {
        const float4 p0 = lp[i2], p1 = lp[i2 + 1];
        const float v0 = Vb[(size_t)__float_as_int(p0.y) * (kH * kD) + lane];
        const float v1 = Vb[(size_t)__float_as_int(p0.w) * (kH * kD) + lane];
        const float v2 = Vb[(size_t)__float_as_int(p1.y) * (kH * kD) + lane];
        const float v3 = Vb[(size_t)__float_as_int(p1.w) * (kH * kD) + lane];
        oacc = fmaf(fmaxf(p0.x - tau, 0.f), v0, oacc);
        oacc = fmaf(fmaxf(p0.z - tau, 0.f), v1, oacc);
        oacc = fmaf(fmaxf(p1.x - tau, 0.f), v2, oacc);
        oacc = fmaf(fmaxf(p1.z - tau, 0.f), v3, oacc);
      }
      for (; i2 < np; ++i2) {
        const float4 p0 = lp[i2];
        const float v0 = Vb[(size_t)__float_as_int(p0.y) * (kH * kD) + lane];
        const float v1 = Vb[(size_t)__float_as_int(p0.w) * (kH * kD) + lane];
        oacc = fmaf(fmaxf(p0.x - tau, 0.f), v0, oacc);
        oacc = fmaf(fmaxf(p0.z - tau, 0.f), v1, oacc);
      }
      if (n & 1) {
        const float2 e = lists[row * CAP + n - 1];
        oacc = fmaf(fmaxf(e.x - tau, 0.f),
                    Vb[(size_t)__float_as_int(e.y) * (kH * kD) + lane], oacc);
      }
    } else {
      // ---- cold exact fallback (list overflow): dense recompute ----
      float scr2[16];
      for (int cc = 0; cc < 16; ++cc) {
        const int j = lane + 64 * cc;
        const float* kr = Kbh + (size_t)j * (kH * kE);
        float zz = 0.f;
        for (int e8 = 0; e8 < 8; ++e8) {
          const f16x8 qh = __builtin_bit_cast(f16x8, Qsh[row * 8 + (e8 ^ (row & 7))]);
          const float4* kp = (const float4*)(kr + e8 * 8);
          const float4 c0 = kp[0], c1 = kp[1];
          zz += (float)qh[0] * c0.x + (float)qh[1] * c0.y + (float)qh[2] * c0.z +
                (float)qh[3] * c0.w + (float)qh[4] * c1.x + (float)qh[5] * c1.y +
                (float)qh[6] * c1.z + (float)qh[7] * c1.w;
        }
        scr2[cc] = zz;
      }
      const float M2 =
          fmaxf(fmaxf(rmax_s[row][0], rmax_s[row][1]), fmaxf(rmax_s[row][2], rmax_s[row][3]));
      float t0 = M2 - 1.0f;
      for (int it = 0; it < 48; ++it) {
        float s = 0.f, c = 0.f;
        for (int cc = 0; cc < 16; ++cc) {
          const float d = scr2[cc] - t0;
          if (d > 0.f) { s += d; c += 1.f; }
        }
        for (int off = 32; off; off >>= 1) { s += __shfl_xor(s, off); c += __shfl_xor(c, off); }
        const float delta = (s - 1.0f) / fmaxf(c, 1.f);
        if (delta <= 1e-7f) break;
        t0 += delta;
      }
      for (int cc = 0; cc < 16; ++cc)
        for (int src = 0; src < 64; ++src) {
          const float z = __shfl(scr2[cc], src);
          const float p = z - t0;
          if (p > 0.f)
            oacc = fmaf(p, Vb[(size_t)(src + 64 * cc) * (kH * kD) + lane], oacc);
        }
    }
    O[(((size_t)(b * kL + l0 + row)) * kH + h) * kD + lane] = oacc;
  }
}

extern "C" void kernel_launch(void* const* d_in, const int* in_sizes, int n_in,
                              void* d_out, int out_size, void* d_ws, size_t ws_size,
                              hipStream_t stream) {
  (void)in_sizes; (void)n_in; (void)out_size; (void)d_ws; (void)ws_size;
  const float* Q = (const float*)d_in[0];
  const float* K = (const float*)d_in[1];
  const float* V = (const float*)d_in[2];
  float* O = (float*)d_out;
  sparsemax_attn<<<dim3(kB * kH * (kL / LT)), dim3(256), 0, stream>>>(Q, K, V, O);
}

// Round 8
// 512.809 us; speedup vs baseline: 2.8782x; 1.1017x over previous
//
#include <hip/hip_runtime.h>

// Sparsemax attention: B=8, L=1024, S=1024, H=16, E=64, D=64, fp32 in/out.
// r8 = r7 + LT=32 with 512 threads (2 row-groups x 4 col-groups):
// K staging amortized over 2x rows, 4 waves/SIMD occupancy.
// QK^T via fp16 MFMA, per-wave running-max candidate filter (valid lower
// bound on tau*), Newton sparsemax on candidate lists, sparse A*V.

typedef _Float16 f16x8 __attribute__((ext_vector_type(8)));
typedef float    f32x4 __attribute__((ext_vector_type(4)));

constexpr int kB = 8, kL = 1024, kS = 1024, kH = 16, kE = 64, kD = 64;
constexpr int LT   = 32;          // L rows per block (2 row-groups of 16)
constexpr int JT   = 128;         // S cols per staged K tile
constexpr int CAP  = 192;         // candidate capacity per row
constexpr int KMAX = CAP / 16;    // Newton regs per lane (16 lanes per row)

__device__ __forceinline__ float pk2(float a, float b) {
  auto h = __builtin_amdgcn_cvt_pkrtz(a, b);
  return __builtin_bit_cast(float, h);
}

__global__ __launch_bounds__(512, 4)
void sparsemax_attn(const float* __restrict__ Q, const float* __restrict__ K,
                    const float* __restrict__ V, float* __restrict__ O) {
  __shared__ float4 Ksh[JT * 8];       // 16 KB fp16 K tile, swizzled slot^(row&7)
  __shared__ float4 Qsh[LT * 8];       //  4 KB fp16 Q tile (scale folded)
  __shared__ float2 lists[LT * CAP];   // 48 KB (z, j-as-float)
  __shared__ int    cnt_s[LT];
  __shared__ float  rmax_s[LT][4];
  __shared__ float  tau_s[LT];

  const int t = threadIdx.x, lane = t & 63, w = t >> 6;
  const int rgp = w >> 2, cg = w & 3;      // row-group, col-group
  const int li = lane & 15, g = lane >> 4;

  // XCD-aware remap: round-robin id%8 -> XCD; same-XCD blocks share few bh.
  const int id  = blockIdx.x;              // 4096 blocks
  const int xcd = id & 7, kk = id >> 3;
  const int bh  = xcd * 16 + (kk >> 5);    // 16 bh per XCD, slow-varying
  const int b   = bh >> 4, h = bh & 15;
  const int l0  = (kk & 31) * LT;

  const float* Kbh = K + ((size_t)b * kS * kH + h) * kE;
  const float* Vb  = V + ((size_t)b * kS * kH + h) * kD;

  if (t < LT) cnt_s[t] = 0;
  if (t < 256) {  // stage Q: 32 rows x 8 slots of 8 halfs
    const int jj = t >> 3, e8 = t & 7;
    const float4* qp =
        (const float4*)(Q + (((size_t)(b * kL + l0 + jj)) * kH + h) * kE + e8 * 8);
    float4 q0 = qp[0], q1 = qp[1];
    q0.x *= .125f; q0.y *= .125f; q0.z *= .125f; q0.w *= .125f;
    q1.x *= .125f; q1.y *= .125f; q1.z *= .125f; q1.w *= .125f;
    Qsh[jj * 8 + (e8 ^ (jj & 7))] =
        make_float4(pk2(q0.x, q0.y), pk2(q0.z, q0.w), pk2(q1.x, q1.y), pk2(q1.z, q1.w));
  }

  float run[4] = {-1e30f, -1e30f, -1e30f, -1e30f};
  f16x8 a0, a1;

  for (int jt = 0; jt < kS / JT; ++jt) {
    __syncthreads();
    // stage K tile: 128 rows x 64 halfs; 2 units per thread
#pragma unroll
    for (int i = 0; i < 2; ++i) {
      const int idx = t + 512 * i, jj = idx >> 3, e8 = idx & 7;
      const float4* kp =
          (const float4*)(Kbh + (size_t)(jt * JT + jj) * (kH * kE) + e8 * 8);
      const float4 c0 = kp[0], c1 = kp[1];
      Ksh[jj * 8 + (e8 ^ (jj & 7))] =
          make_float4(pk2(c0.x, c0.y), pk2(c0.z, c0.w), pk2(c1.x, c1.y), pk2(c1.z, c1.w));
    }
    __syncthreads();
    if (jt == 0) {  // A-frags: Q row = rgp*16 + li, k-chunks g and 4+g
      const int qr = rgp * 16 + li;
      a0 = __builtin_bit_cast(f16x8, Qsh[qr * 8 + ((0 + g) ^ (qr & 7))]);
      a1 = __builtin_bit_cast(f16x8, Qsh[qr * 8 + ((4 + g) ^ (qr & 7))]);
    }

    f32x4 acc[2];
    acc[0] = f32x4{0.f, 0.f, 0.f, 0.f};
    acc[1] = f32x4{0.f, 0.f, 0.f, 0.f};
#pragma unroll
    for (int ct = 0; ct < 2; ++ct) {  // col-group cg covers cols cg*32 + ct*16 + li
      const int jl = cg * 32 + ct * 16 + li;
      const f16x8 b0 = __builtin_bit_cast(f16x8, Ksh[jl * 8 + ((0 + g) ^ (jl & 7))]);
      const f16x8 b1 = __builtin_bit_cast(f16x8, Ksh[jl * 8 + ((4 + g) ^ (jl & 7))]);
      acc[ct] = __builtin_amdgcn_mfma_f32_16x16x32_f16(a0, b0, acc[ct], 0, 0, 0);
      acc[ct] = __builtin_amdgcn_mfma_f32_16x16x32_f16(a1, b1, acc[ct], 0, 0, 0);
    }

    // filter: C-layout row = rgp*16 + g*4 + r, col = cg*32 + ct*16 + li
#pragma unroll
    for (int r = 0; r < 4; ++r) {
      const int row = rgp * 16 + g * 4 + r;
      float mr = fmaxf(acc[0][r], acc[1][r]);
      mr = fmaxf(mr, __shfl_xor(mr, 1));
      mr = fmaxf(mr, __shfl_xor(mr, 2));
      mr = fmaxf(mr, __shfl_xor(mr, 4));
      mr = fmaxf(mr, __shfl_xor(mr, 8));
      run[r] = fmaxf(run[r], mr);          // col-group partial running max
      const float thr = run[r] - 1.0f;     // <= rowmax-1 <= tau*: superset filter
#pragma unroll
      for (int ct = 0; ct < 2; ++ct) {
        const float z = acc[ct][r];
        if (z > thr) {
          const int pos = atomicAdd(&cnt_s[row], 1);
          if (pos < CAP)
            lists[row * CAP + pos] =
                make_float2(z, __int_as_float(jt * JT + cg * 32 + ct * 16 + li));
        }
      }
    }
  }
  if (li == 0) {
#pragma unroll
    for (int r = 0; r < 4; ++r) rmax_s[rgp * 16 + g * 4 + r][cg] = run[r];
  }
  __syncthreads();

  // ---- Newton: wave w owns rows w*4..+3; row w*4+g, 16 lanes each ----
  const int q0 = w * 4;
  {
    const int row = q0 + g;
    const int n   = cnt_s[row];
    const int nc  = min(n, CAP);
    float zr[KMAX];
#pragma unroll
    for (int k = 0; k < KMAX; ++k) {
      const int i = li + 16 * k;
      zr[k] = (i < nc) ? lists[row * CAP + i].x : -1e30f;
    }
    const float M =
        fmaxf(fmaxf(rmax_s[row][0], rmax_s[row][1]), fmaxf(rmax_s[row][2], rmax_s[row][3]));
    float t0 = M - 1.0f;
    for (int it = 0; it < 14; ++it) {
      float s = 0.f, c = 0.f;
#pragma unroll
      for (int k = 0; k < KMAX; ++k) {
        const float d = zr[k] - t0;
        if (d > 0.f) { s += d; c += 1.f; }
      }
      s += __shfl_xor(s, 1); c += __shfl_xor(c, 1);
      s += __shfl_xor(s, 2); c += __shfl_xor(c, 2);
      s += __shfl_xor(s, 4); c += __shfl_xor(c, 4);
      s += __shfl_xor(s, 8); c += __shfl_xor(c, 8);
      const float delta = (s - 1.0f) / fmaxf(c, 1.f);
      t0 += fmaxf(delta, 0.f);
      if (__all(delta <= 1e-6f)) break;
    }
    if (li == 0) tau_s[row] = t0;
  }

  // ---- sparse A*V: lane = output dim d; wave w does rows w*4..w*4+3 ----
#pragma unroll 1
  for (int r4 = 0; r4 < 4; ++r4) {
    const int row = q0 + r4;
    const int n   = cnt_s[row];
    float oacc = 0.f;
    if (n <= CAP) {
      const float tau = tau_s[row];
      const float4* lp = (const float4*)(lists + row * CAP);
      const int np = n >> 1;
      int i2 = 0;
      for (; i2 + 2 <= np; i2 += 2) {
        const float4 p0 = lp[i2], p1 = lp[i2 + 1];
        const float v0 = Vb[(size_t)__float_as_int(p0.y) * (kH * kD) + lane];
        const float v1 = Vb[(size_t)__float_as_int(p0.w) * (kH * kD) + lane];
        const float v2 = Vb[(size_t)__float_as_int(p1.y) * (kH * kD) + lane];
        const float v3 = Vb[(size_t)__float_as_int(p1.w) * (kH * kD) + lane];
        oacc = fmaf(fmaxf(p0.x - tau, 0.f), v0, oacc);
        oacc = fmaf(fmaxf(p0.z - tau, 0.f), v1, oacc);
        oacc = fmaf(fmaxf(p1.x - tau, 0.f), v2, oacc);
        oacc = fmaf(fmaxf(p1.z - tau, 0.f), v3, oacc);
      }
      for (; i2 < np; ++i2) {
        const float4 p0 = lp[i2];
        const float v0 = Vb[(size_t)__float_as_int(p0.y) * (kH * kD) + lane];
        const float v1 = Vb[(size_t)__float_as_int(p0.w) * (kH * kD) + lane];
        oacc = fmaf(fmaxf(p0.x - tau, 0.f), v0, oacc);
        oacc = fmaf(fmaxf(p0.z - tau, 0.f), v1, oacc);
      }
      if (n & 1) {
        const float2 e = lists[row * CAP + n - 1];
        oacc = fmaf(fmaxf(e.x - tau, 0.f),
                    Vb[(size_t)__float_as_int(e.y) * (kH * kD) + lane], oacc);
      }
    } else {
      // ---- cold exact fallback (list overflow): dense recompute ----
      float scr2[16];
      for (int cc = 0; cc < 16; ++cc) {
        const int j = lane + 64 * cc;
        const float* kr = Kbh + (size_t)j * (kH * kE);
        float zz = 0.f;
        for (int e8 = 0; e8 < 8; ++e8) {
          const f16x8 qh = __builtin_bit_cast(f16x8, Qsh[row * 8 + (e8 ^ (row & 7))]);
          const float4* kp = (const float4*)(kr + e8 * 8);
          const float4 c0 = kp[0], c1 = kp[1];
          zz += (float)qh[0] * c0.x + (float)qh[1] * c0.y + (float)qh[2] * c0.z +
                (float)qh[3] * c0.w + (float)qh[4] * c1.x + (float)qh[5] * c1.y +
                (float)qh[6] * c1.z + (float)qh[7] * c1.w;
        }
        scr2[cc] = zz;
      }
      const float M2 =
          fmaxf(fmaxf(rmax_s[row][0], rmax_s[row][1]), fmaxf(rmax_s[row][2], rmax_s[row][3]));
      float t0 = M2 - 1.0f;
      for (int it = 0; it < 48; ++it) {
        float s = 0.f, c = 0.f;
        for (int cc = 0; cc < 16; ++cc) {
          const float d = scr2[cc] - t0;
          if (d > 0.f) { s += d; c += 1.f; }
        }
        for (int off = 32; off; off >>= 1) { s += __shfl_xor(s, off); c += __shfl_xor(c, off); }
        const float delta = (s - 1.0f) / fmaxf(c, 1.f);
        if (delta <= 1e-7f) break;
        t0 += delta;
      }
      for (int cc = 0; cc < 16; ++cc)
        for (int src = 0; src < 64; ++src) {
          const float z = __shfl(scr2[cc], src);
          const float p = z - t0;
          if (p > 0.f)
            oacc = fmaf(p, Vb[(size_t)(src + 64 * cc) * (kH * kD) + lane], oacc);
        }
    }
    O[(((size_t)(b * kL + l0 + row)) * kH + h) * kD + lane] = oacc;
  }
}

extern "C" void kernel_launch(void* const* d_in, const int* in_sizes, int n_in,
                              void* d_out, int out_size, void* d_ws, size_t ws_size,
                              hipStream_t stream) {
  (void)in_sizes; (void)n_in; (void)out_size; (void)d_ws; (void)ws_size;
  const float* Q = (const float*)d_in[0];
  const float* K = (const float*)d_in[1];
  const float* V = (const float*)d_in[2];
  float* O = (float*)d_out;
  sparsemax_attn<<<dim3(kB * kH * (kL / LT)), dim3(512), 0, stream>>>(Q, K, V, O);
}

// Round 9
// 496.141 us; speedup vs baseline: 2.9749x; 1.0336x over previous
//
#include <hip/hip_runtime.h>

// Sparsemax attention: B=8, L=1024, S=1024, H=16, E=64, D=64, fp32 in/out.
// r9 = r8 + (1) operand-swapped MFMA (A=K, B=Q): each lane owns ONE output
// row -> per-tile filter is a per-lane fmax tree + 2 shuffles (was 16);
// (2) g-parallel float4 epilogue. XCD remap, LT=32/512 threads, CAP=192 kept.

typedef _Float16 f16x8 __attribute__((ext_vector_type(8)));
typedef float    f32x4 __attribute__((ext_vector_type(4)));

constexpr int kB = 8, kL = 1024, kS = 1024, kH = 16, kE = 64, kD = 64;
constexpr int LT   = 32;          // L rows per block (2 query-groups of 16)
constexpr int JT   = 128;         // S cols per staged K tile
constexpr int CAP  = 192;         // candidate capacity per row
constexpr int KMAX = CAP / 16;    // Newton regs per lane (16 lanes per row)

__device__ __forceinline__ float pk2(float a, float b) {
  auto h = __builtin_amdgcn_cvt_pkrtz(a, b);
  return __builtin_bit_cast(float, h);
}

__global__ __launch_bounds__(512, 4)
void sparsemax_attn(const float* __restrict__ Q, const float* __restrict__ K,
                    const float* __restrict__ V, float* __restrict__ O) {
  __shared__ float4 Ksh[JT * 8];       // 16 KB fp16 K tile, swizzled slot^(row&7)
  __shared__ float4 Qsh[LT * 8];       //  4 KB fp16 Q tile (scale folded)
  __shared__ float2 lists[LT * CAP];   // 48 KB (z, j-as-float)
  __shared__ int    cnt_s[LT];
  __shared__ float  rmax_s[LT][4];
  __shared__ float  tau_s[LT];

  const int t = threadIdx.x, lane = t & 63, w = t >> 6;
  const int qg = w >> 2, jg = w & 3;       // query-group, j-group
  const int li = lane & 15, g = lane >> 4;
  const int myrow = qg * 16 + li;          // the ONE output row this lane serves

  // XCD-aware remap: round-robin id%8 -> XCD; same-XCD blocks share few bh.
  const int id  = blockIdx.x;              // 4096 blocks
  const int xcd = id & 7, kk = id >> 3;
  const int bh  = xcd * 16 + (kk >> 5);    // 16 bh per XCD, slow-varying
  const int b   = bh >> 4, h = bh & 15;
  const int l0  = (kk & 31) * LT;

  const float* Kbh = K + ((size_t)b * kS * kH + h) * kE;
  const float* Vb  = V + ((size_t)b * kS * kH + h) * kD;

  if (t < LT) cnt_s[t] = 0;
  if (t < 256) {  // stage Q: 32 rows x 8 slots of 8 halfs
    const int jj = t >> 3, e8 = t & 7;
    const float4* qp =
        (const float4*)(Q + (((size_t)(b * kL + l0 + jj)) * kH + h) * kE + e8 * 8);
    float4 q0 = qp[0], q1 = qp[1];
    q0.x *= .125f; q0.y *= .125f; q0.z *= .125f; q0.w *= .125f;
    q1.x *= .125f; q1.y *= .125f; q1.z *= .125f; q1.w *= .125f;
    Qsh[jj * 8 + (e8 ^ (jj & 7))] =
        make_float4(pk2(q0.x, q0.y), pk2(q0.z, q0.w), pk2(q1.x, q1.y), pk2(q1.z, q1.w));
  }

  float runl = -1e30f;    // per-lane cumulative max over seen scores of myrow
  f16x8 b0, b1;           // cached Q fragments (B operand)

  for (int jt = 0; jt < kS / JT; ++jt) {
    __syncthreads();
    // stage K tile: 128 rows x 64 halfs; 2 units per thread
#pragma unroll
    for (int i = 0; i < 2; ++i) {
      const int idx = t + 512 * i, jj = idx >> 3, e8 = idx & 7;
      const float4* kp =
          (const float4*)(Kbh + (size_t)(jt * JT + jj) * (kH * kE) + e8 * 8);
      const float4 c0 = kp[0], c1 = kp[1];
      Ksh[jj * 8 + (e8 ^ (jj & 7))] =
          make_float4(pk2(c0.x, c0.y), pk2(c0.z, c0.w), pk2(c1.x, c1.y), pk2(c1.z, c1.w));
    }
    __syncthreads();
    if (jt == 0) {  // B-frags: Q[row = myrow][k-chunks g, 4+g] (k-contiguous)
      b0 = __builtin_bit_cast(f16x8, Qsh[myrow * 8 + ((0 + g) ^ (myrow & 7))]);
      b1 = __builtin_bit_cast(f16x8, Qsh[myrow * 8 + ((4 + g) ^ (myrow & 7))]);
    }

    f32x4 acc[2];
    acc[0] = f32x4{0.f, 0.f, 0.f, 0.f};
    acc[1] = f32x4{0.f, 0.f, 0.f, 0.f};
#pragma unroll
    for (int ct = 0; ct < 2; ++ct) {  // A = K rows jl (m dim = j)
      const int jl = jg * 32 + ct * 16 + li;
      const f16x8 a0 = __builtin_bit_cast(f16x8, Ksh[jl * 8 + ((0 + g) ^ (jl & 7))]);
      const f16x8 a1 = __builtin_bit_cast(f16x8, Ksh[jl * 8 + ((4 + g) ^ (jl & 7))]);
      acc[ct] = __builtin_amdgcn_mfma_f32_16x16x32_f16(a0, b0, acc[ct], 0, 0, 0);
      acc[ct] = __builtin_amdgcn_mfma_f32_16x16x32_f16(a1, b1, acc[ct], 0, 0, 0);
    }
    // D[j = jt*128 + jg*32 + ct*16 + g*4 + reg][query = myrow]

    // ---- filter: per-lane max tree + 2-shuffle g-reduce ----
    const float m01 = fmaxf(fmaxf(acc[0][0], acc[0][1]), fmaxf(acc[0][2], acc[0][3]));
    const float m23 = fmaxf(fmaxf(acc[1][0], acc[1][1]), fmaxf(acc[1][2], acc[1][3]));
    runl = fmaxf(runl, fmaxf(m01, m23));
    float mr = fmaxf(runl, __shfl_xor(runl, 16));
    mr = fmaxf(mr, __shfl_xor(mr, 32));
    const float thr = mr - 1.0f;  // <= rowmax-1 <= tau*: superset filter
    const int jbase = jt * JT + jg * 32 + g * 4;
#pragma unroll
    for (int ct = 0; ct < 2; ++ct)
#pragma unroll
      for (int r = 0; r < 4; ++r) {
        const float z = acc[ct][r];
        if (z > thr) {
          const int pos = atomicAdd(&cnt_s[myrow], 1);
          if (pos < CAP)
            lists[myrow * CAP + pos] =
                make_float2(z, __int_as_float(jbase + ct * 16 + r));
        }
      }
  }
  {
    float mr = fmaxf(runl, __shfl_xor(runl, 16));
    mr = fmaxf(mr, __shfl_xor(mr, 32));
    if (lane < 16) rmax_s[myrow][jg] = mr;
  }
  __syncthreads();

  // ---- Newton: wave w owns rows w*4..+3; row w*4+g, 16 lanes each ----
  const int q0 = w * 4;
  {
    const int row = q0 + g;
    const int n   = cnt_s[row];
    const int nc  = min(n, CAP);
    float zr[KMAX];
#pragma unroll
    for (int k = 0; k < KMAX; ++k) {
      const int i = li + 16 * k;
      zr[k] = (i < nc) ? lists[row * CAP + i].x : -1e30f;
    }
    const float M =
        fmaxf(fmaxf(rmax_s[row][0], rmax_s[row][1]), fmaxf(rmax_s[row][2], rmax_s[row][3]));
    float t0 = M - 1.0f;
    for (int it = 0; it < 14; ++it) {
      float s = 0.f, c = 0.f;
#pragma unroll
      for (int k = 0; k < KMAX; ++k) {
        const float d = zr[k] - t0;
        if (d > 0.f) { s += d; c += 1.f; }
      }
      s += __shfl_xor(s, 1); c += __shfl_xor(c, 1);
      s += __shfl_xor(s, 2); c += __shfl_xor(c, 2);
      s += __shfl_xor(s, 4); c += __shfl_xor(c, 4);
      s += __shfl_xor(s, 8); c += __shfl_xor(c, 8);
      const float delta = (s - 1.0f) / fmaxf(c, 1.f);
      t0 += fmaxf(delta, 0.f);
      if (__all(delta <= 1e-6f)) break;
    }
    if (li == 0) tau_s[row] = t0;
  }

  // ---- sparse A*V: 4 candidates concurrent (one per g), float4 over dims ----
#pragma unroll 1
  for (int r4 = 0; r4 < 4; ++r4) {
    const int row = q0 + r4;
    const int n   = cnt_s[row];
    const size_t obase = (((size_t)(b * kL + l0 + row)) * kH + h) * kD;
    if (n <= CAP) {
      const float tau = tau_s[row];
      f32x4 o4 = {0.f, 0.f, 0.f, 0.f};
      for (int i = g; i < n; i += 4) {
        const float2 e = lists[row * CAP + i];
        const float  p = fmaxf(e.x - tau, 0.f);
        const float4 v =
            ((const float4*)(Vb + (size_t)__float_as_int(e.y) * (kH * kD)))[li];
        o4.x = fmaf(p, v.x, o4.x);
        o4.y = fmaf(p, v.y, o4.y);
        o4.z = fmaf(p, v.z, o4.z);
        o4.w = fmaf(p, v.w, o4.w);
      }
      o4.x += __shfl_xor(o4.x, 16); o4.y += __shfl_xor(o4.y, 16);
      o4.z += __shfl_xor(o4.z, 16); o4.w += __shfl_xor(o4.w, 16);
      o4.x += __shfl_xor(o4.x, 32); o4.y += __shfl_xor(o4.y, 32);
      o4.z += __shfl_xor(o4.z, 32); o4.w += __shfl_xor(o4.w, 32);
      if (lane < 16)
        ((float4*)(O + obase))[li] = make_float4(o4.x, o4.y, o4.z, o4.w);
    } else {
      // ---- cold exact fallback (list overflow): dense recompute ----
      float scr2[16];
      for (int cc = 0; cc < 16; ++cc) {
        const int j = lane + 64 * cc;
        const float* kr = Kbh + (size_t)j * (kH * kE);
        float zz = 0.f;
        for (int e8 = 0; e8 < 8; ++e8) {
          const f16x8 qh = __builtin_bit_cast(f16x8, Qsh[row * 8 + (e8 ^ (row & 7))]);
          const float4* kp = (const float4*)(kr + e8 * 8);
          const float4 c0 = kp[0], c1 = kp[1];
          zz += (float)qh[0] * c0.x + (float)qh[1] * c0.y + (float)qh[2] * c0.z +
                (float)qh[3] * c0.w + (float)qh[4] * c1.x + (float)qh[5] * c1.y +
                (float)qh[6] * c1.z + (float)qh[7] * c1.w;
        }
        scr2[cc] = zz;
      }
      const float M2 =
          fmaxf(fmaxf(rmax_s[row][0], rmax_s[row][1]), fmaxf(rmax_s[row][2], rmax_s[row][3]));
      float t0 = M2 - 1.0f;
      for (int it = 0; it < 48; ++it) {
        float s = 0.f, c = 0.f;
        for (int cc = 0; cc < 16; ++cc) {
          const float d = scr2[cc] - t0;
          if (d > 0.f) { s += d; c += 1.f; }
        }
        for (int off = 32; off; off >>= 1) { s += __shfl_xor(s, off); c += __shfl_xor(c, off); }
        const float delta = (s - 1.0f) / fmaxf(c, 1.f);
        if (delta <= 1e-7f) break;
        t0 += delta;
      }
      float oacc = 0.f;
      for (int cc = 0; cc < 16; ++cc)
        for (int src = 0; src < 64; ++src) {
          const float z = __shfl(scr2[cc], src);
          const float p = z - t0;
          if (p > 0.f)
            oacc = fmaf(p, Vb[(size_t)(src + 64 * cc) * (kH * kD) + lane], oacc);
        }
      O[obase + lane] = oacc;
    }
  }
}

extern "C" void kernel_launch(void* const* d_in, const int* in_sizes, int n_in,
                              void* d_out, int out_size, void* d_ws, size_t ws_size,
                              hipStream_t stream) {
  (void)in_sizes; (void)n_in; (void)out_size; (void)d_ws; (void)ws_size;
  const float* Q = (const float*)d_in[0];
  const float* K = (const float*)d_in[1];
  const float* V = (const float*)d_in[2];
  float* O = (float*)d_out;
  sparsemax_attn<<<dim3(kB * kH * (kL / LT)), dim3(512), 0, stream>>>(Q, K, V, O);
}